// Round 10
// baseline (344.443 us; speedup 1.0000x reference)
//
#include <hip/hip_runtime.h>
#include <cstdint>
#include <cstddef>

#define Bc 4
#define Tc 2048
#define Cc 1024
#define Hc 16
#define Dc 64

typedef unsigned short ushort_t;
typedef __bf16 v8bf __attribute__((ext_vector_type(8)));
typedef float v4f __attribute__((ext_vector_type(4)));

__device__ inline ushort_t f2bf(float f) {
  union { float f; unsigned int u; } v; v.f = f;
  unsigned int r = v.u + 0x7fffu + ((v.u >> 16) & 1u);  // RNE
  return (ushort_t)(r >> 16);
}

__device__ inline unsigned int pack2bf(float lo, float hi) {
  return (unsigned int)f2bf(lo) | ((unsigned int)f2bf(hi) << 16);
}

// async global->LDS, 16B per lane. LDS dest: wave-uniform base; HW adds lane*16.
__device__ inline void gl_lds16(const void* g, void* l) {
  __builtin_amdgcn_global_load_lds((__attribute__((address_space(1))) void*)g,
                                   (__attribute__((address_space(3))) void*)l,
                                   16, 0, 0);
}

// float -> bf16 elementwise
__global__ void cvt_bf16(const float* __restrict__ in, ushort_t* __restrict__ out, int n) {
  int i = blockIdx.x * blockDim.x + threadIdx.x;
  if (i < n) out[i] = f2bf(in[i]);
}

// w [K,N] f32 -> wt [N,K] bf16, tiled via LDS (coalesced both sides)
__global__ __launch_bounds__(256) void transpose_bf16t(const float* __restrict__ w,
                                                       ushort_t* __restrict__ wt,
                                                       int K, int N) {
  __shared__ float tile[64][65];
  const int t = threadIdx.x;
  const int n0 = blockIdx.x * 64;
  const int k0 = blockIdx.y * 64;
  #pragma unroll
  for (int i = 0; i < 16; ++i) {
    int r = (t >> 6) + i * 4, c = t & 63;
    tile[r][c] = w[(size_t)(k0 + r) * N + n0 + c];
  }
  __syncthreads();
  #pragma unroll
  for (int i = 0; i < 16; ++i) {
    int r = (t >> 6) + i * 4, c = t & 63;
    wt[(size_t)(n0 + r) * K + k0 + c] = f2bf(tile[c][r]);
  }
}

// 128x128 GEMM, BK=32, 4 waves, 2-phase double-buffered.
// NEW vs prev round: B-operand bypasses LDS entirely. Each wave loads its own
// B-fragments global->register (L2-resident weights), double-buffered one iter
// ahead; A stays gl_lds16-staged/dbuf'd. Halves LDS staging writes and per-wave
// ds_reads (8 b128 -> 4): LDS pipe was the measured saturated resource
// (~800 cyc demand vs 855 budget per block-iter; MfmaUtil 25%).
// Loop body manually processes TWO k-steps so the register buffers (bregA/
// bregB) are compile-time-indexed (rule #20: runtime-indexed vector arrays
// spill to scratch). NK is even for all our shapes (K=1024/32=32).
// C = A[M,K] * BT[N,K]^T + bias.
// MODE 0: fp32 C[M,N].  MODE 1: qkv epilogue (Q/K rows, V transposed).
template <int MODE>
__global__ __launch_bounds__(256) void gemm128(const ushort_t* __restrict__ A,
                                               const ushort_t* __restrict__ BT,
                                               const float* __restrict__ bias,
                                               float* __restrict__ Cout,
                                               ushort_t* __restrict__ Qb,
                                               ushort_t* __restrict__ Kb,
                                               ushort_t* __restrict__ Vt,
                                               int M, int N, int K) {
  // 2 x 8 KB A-buffers; MODE1 epilogue Cs (18432 B) reuses the same space.
  __shared__ __align__(16) unsigned char smem[18432];

  const int t = threadIdx.x;
  const int wave = t >> 6;
  const int lane = t & 63;
  const int quad = lane >> 4;
  const int l15 = lane & 15;
  const int m0 = blockIdx.y * 128;
  const int n0 = blockIdx.x * 128;
  const int wm = wave >> 1, wn = wave & 1;

  v4f acc[4][4];
  #pragma unroll
  for (int mi = 0; mi < 4; ++mi)
    #pragma unroll
    for (int ni = 0; ni < 4; ++ni) acc[mi][ni] = (v4f){0.f, 0.f, 0.f, 0.f};

  const int NK = K >> 5;   // K / 32 (even)

  // A staging address pieces (512 16B segments, 2 per thread)
  const int srow0 = t >> 2, ssc = (t & 3) * 8;
  const int srow1 = (t + 256) >> 2;
  const int sbase0 = (t & ~63) * 8;
  const int sbase1 = ((t & ~63) + 256) * 8;

  // B row pointers (per-lane), k advances via offset
  const ushort_t* bp0 = BT + (size_t)(n0 + wn * 64 + 0 * 16 + l15) * K + quad * 8;
  const ushort_t* bp1 = BT + (size_t)(n0 + wn * 64 + 1 * 16 + l15) * K + quad * 8;
  const ushort_t* bp2 = BT + (size_t)(n0 + wn * 64 + 2 * 16 + l15) * K + quad * 8;
  const ushort_t* bp3 = BT + (size_t)(n0 + wn * 64 + 3 * 16 + l15) * K + quad * 8;

  v8bf bA0, bA1, bA2, bA3, bB0, bB1, bB2, bB3;

  // prologue: stage A(k=0) into buf0; load B(k=0) into bregA
  {
    ushort_t* As = (ushort_t*)smem;
    gl_lds16(A + (size_t)(m0 + srow0) * K + ssc, &As[sbase0]);
    gl_lds16(A + (size_t)(m0 + srow1) * K + ssc, &As[sbase1]);
    bA0 = *reinterpret_cast<const v8bf*>(bp0);
    bA1 = *reinterpret_cast<const v8bf*>(bp1);
    bA2 = *reinterpret_cast<const v8bf*>(bp2);
    bA3 = *reinterpret_cast<const v8bf*>(bp3);
  }

  for (int kk = 0; kk < NK; kk += 2) {
    // ---- even step: compute buf0 + bregA; prefetch k+1 into buf1 + bregB ----
    __syncthreads();
    {
      const int kc = (kk + 1) * 32;          // kk+1 <= NK-1 always exists
      ushort_t* As = (ushort_t*)(smem + 8192);
      gl_lds16(A + (size_t)(m0 + srow0) * K + kc + ssc, &As[sbase0]);
      gl_lds16(A + (size_t)(m0 + srow1) * K + kc + ssc, &As[sbase1]);
      bB0 = *reinterpret_cast<const v8bf*>(bp0 + kc);
      bB1 = *reinterpret_cast<const v8bf*>(bp1 + kc);
      bB2 = *reinterpret_cast<const v8bf*>(bp2 + kc);
      bB3 = *reinterpret_cast<const v8bf*>(bp3 + kc);
    }
    {
      const ushort_t* As = (const ushort_t*)smem;
      v8bf a[4];
      #pragma unroll
      for (int mi = 0; mi < 4; ++mi)
        a[mi] = *reinterpret_cast<const v8bf*>(&As[(wm * 64 + mi * 16 + l15) * 32 + quad * 8]);
      #pragma unroll
      for (int mi = 0; mi < 4; ++mi) {
        acc[mi][0] = __builtin_amdgcn_mfma_f32_16x16x32_bf16(a[mi], bA0, acc[mi][0], 0, 0, 0);
        acc[mi][1] = __builtin_amdgcn_mfma_f32_16x16x32_bf16(a[mi], bA1, acc[mi][1], 0, 0, 0);
        acc[mi][2] = __builtin_amdgcn_mfma_f32_16x16x32_bf16(a[mi], bA2, acc[mi][2], 0, 0, 0);
        acc[mi][3] = __builtin_amdgcn_mfma_f32_16x16x32_bf16(a[mi], bA3, acc[mi][3], 0, 0, 0);
      }
    }
    // ---- odd step: compute buf1 + bregB; prefetch k+2 into buf0 + bregA ----
    __syncthreads();
    if (kk + 2 < NK) {
      const int kc = (kk + 2) * 32;
      ushort_t* As = (ushort_t*)smem;
      gl_lds16(A + (size_t)(m0 + srow0) * K + kc + ssc, &As[sbase0]);
      gl_lds16(A + (size_t)(m0 + srow1) * K + kc + ssc, &As[sbase1]);
      bA0 = *reinterpret_cast<const v8bf*>(bp0 + kc);
      bA1 = *reinterpret_cast<const v8bf*>(bp1 + kc);
      bA2 = *reinterpret_cast<const v8bf*>(bp2 + kc);
      bA3 = *reinterpret_cast<const v8bf*>(bp3 + kc);
    }
    {
      const ushort_t* As = (const ushort_t*)(smem + 8192);
      v8bf a[4];
      #pragma unroll
      for (int mi = 0; mi < 4; ++mi)
        a[mi] = *reinterpret_cast<const v8bf*>(&As[(wm * 64 + mi * 16 + l15) * 32 + quad * 8]);
      #pragma unroll
      for (int mi = 0; mi < 4; ++mi) {
        acc[mi][0] = __builtin_amdgcn_mfma_f32_16x16x32_bf16(a[mi], bB0, acc[mi][0], 0, 0, 0);
        acc[mi][1] = __builtin_amdgcn_mfma_f32_16x16x32_bf16(a[mi], bB1, acc[mi][1], 0, 0, 0);
        acc[mi][2] = __builtin_amdgcn_mfma_f32_16x16x32_bf16(a[mi], bB2, acc[mi][2], 0, 0, 0);
        acc[mi][3] = __builtin_amdgcn_mfma_f32_16x16x32_bf16(a[mi], bB3, acc[mi][3], 0, 0, 0);
      }
    }
  }
  __syncthreads();   // all A-buffer reads done; MODE1 may reuse smem for Cs

  // Epilogue. C/D layout: col = lane&15, row = quad*4 + i.
  if (MODE == 0) {
    #pragma unroll
    for (int ni = 0; ni < 4; ++ni) {
      const int n_g = n0 + wn * 64 + ni * 16 + l15;
      const float bv = bias[n_g];
      #pragma unroll
      for (int mi = 0; mi < 4; ++mi)
        #pragma unroll
        for (int i = 0; i < 4; ++i) {
          int m_g = m0 + wm * 64 + mi * 16 + quad * 4 + i;
          Cout[(size_t)m_g * N + n_g] = acc[mi][ni][i] + bv;
        }
    }
  } else {
    const int part = n0 >> 10;          // block-uniform: 0:Q 1:K 2:V
    ushort_t* Cs = (ushort_t*)smem;
    if (part < 2) {
      // two passes of 64 m-rows through [64][136] staging -> [bh,t,d] rows
      ushort_t* dst = (part == 0) ? Qb : Kb;
      #pragma unroll
      for (int p = 0; p < 2; ++p) {
        if (wm == p) {
          #pragma unroll
          for (int ni = 0; ni < 4; ++ni) {
            const int n_l = wn * 64 + ni * 16 + l15;
            const float bv = bias[n0 + n_l];
            #pragma unroll
            for (int mi = 0; mi < 4; ++mi)
              #pragma unroll
              for (int i = 0; i < 4; ++i) {
                int r = mi * 16 + quad * 4 + i;       // local row 0..63
                Cs[r * 136 + n_l] = f2bf(acc[mi][ni][i] + bv);
              }
          }
        }
        __syncthreads();
        const int r = t >> 2, q4 = t & 3;             // 64 rows x 4 quarters
        const int m_g = m0 + p * 64 + r;
        const int bb = m_g >> 11, tt = m_g & 2047;
        const int h = ((n0 & 1023) >> 6) + (q4 >> 1);
        ushort_t* gp = dst + (((size_t)bb * Hc + h) * Tc + tt) * Dc + (q4 & 1) * 32;
        const ushort_t* sp = &Cs[r * 136 + q4 * 32];
        #pragma unroll
        for (int j = 0; j < 4; ++j)
          *reinterpret_cast<uint4*>(gp + j * 8) = *reinterpret_cast<const uint4*>(sp + j * 8);
        __syncthreads();
      }
    } else {
      // V: two passes of 64 m-cols through transposed [128][72] staging
      // -> [bh,d,t] rows
      #pragma unroll
      for (int p = 0; p < 2; ++p) {
        if (wm == p) {
          #pragma unroll
          for (int ni = 0; ni < 4; ++ni) {
            const int n_l = wn * 64 + ni * 16 + l15;
            const float bv = bias[n0 + n_l];
            #pragma unroll
            for (int mi = 0; mi < 4; ++mi)
              #pragma unroll
              for (int i = 0; i < 4; ++i) {
                int c = mi * 16 + quad * 4 + i;       // local m col 0..63
                Cs[n_l * 72 + c] = f2bf(acc[mi][ni][i] + bv);
              }
          }
        }
        __syncthreads();
        const int bb = m0 >> 11, tt0 = m0 & 2047;
        const int h0 = (n0 >> 6) - 32;               // (n0-2048)/64
        const int row = t >> 1, half = t & 1;        // row = n_l
        const int d = row & 63, hh = row >> 6;
        ushort_t* gp = Vt + ((size_t)(bb * Hc + h0 + hh) * Dc + d) * Tc +
                       tt0 + p * 64 + half * 32;
        const ushort_t* sp = &Cs[row * 72 + half * 32];
        #pragma unroll
        for (int j = 0; j < 4; ++j)
          *reinterpret_cast<uint4*>(gp + j * 8) = *reinterpret_cast<const uint4*>(sp + j * 8);
        __syncthreads();
      }
    }
  }
}

// One q-tile slab of flash attention (v10 structure) with the LDS P-transform
// (verified round 9): P written to per-wave scratch (4x ds_write_b64,
// XOR-swizzled) and read back as PV B-fragments (2x ds_read_b128).
__device__ __forceinline__ void flash_body(int jq, int bh, int w, int lane, int quad, int l15,
                                           const ushort_t* __restrict__ Qb,
                                           const ushort_t* __restrict__ Kb,
                                           const ushort_t* __restrict__ Vt,
                                           ushort_t* __restrict__ yb,
                                           ushort_t (*Kbuf)[8 * 512],
                                           ushort_t (*Vbuf)[8 * 512],
                                           ushort_t* __restrict__ Ps) {
  const int ktmax = jq;                        // diag tile index
  const int s = jq * 64 + w * 16;              // this wave's 16 queries

  const ushort_t* Kbh = Kb + (size_t)bh * (Tc * Dc);
  const ushort_t* Vbh = Vt + (size_t)bh * (Dc * Tc);

  // Q B-fragment (n=q=l15, k=d=quad*8+j)
  const ushort_t* qp = Qb + ((size_t)bh * Tc + s + l15) * Dc;
  v8bf q0 = *reinterpret_cast<const v8bf*>(qp + quad * 8);
  v8bf q1 = *reinterpret_cast<const v8bf*>(qp + 32 + quad * 8);

  v4f O[4];
  #pragma unroll
  for (int i = 0; i < 4; ++i) O[i] = (v4f){0.f, 0.f, 0.f, 0.f};
  float ps = 0.f;
  const float SCALE_LOG2E = 0.125f * 1.44269504f;

  // P scratch indices (ushort units), XOR involution on bits 3..5
  const int swz = (l15 & 7) << 3;
  const int prow = l15 * 64;

  // prologue: stage kt=0 into buffer 0 (each wave stages chunks w and w+4)
  #pragma unroll
  for (int it = 0; it < 2; ++it) {
    int c = w + it * 4, nt = c >> 1, ks = c & 1;
    gl_lds16(Kbh + (size_t)(nt * 16 + l15) * Dc + ks * 32 + quad * 8, &Kbuf[0][c * 512]);
    gl_lds16(Vbh + (size_t)(nt * 16 + l15) * Tc + ks * 32 + quad * 8, &Vbuf[0][c * 512]);
  }

  for (int kt = 0; kt <= ktmax; ++kt) {
    __syncthreads();   // staging of buf[kt&1] drained; all waves past compute(kt-1)
    const int cur = kt & 1;
    if (kt < ktmax) {
      const int nxt = cur ^ 1;
      #pragma unroll
      for (int it = 0; it < 2; ++it) {
        int c = w + it * 4, nt = c >> 1, ks = c & 1;
        gl_lds16(Kbh + (size_t)((kt + 1) * 64 + nt * 16 + l15) * Dc + ks * 32 + quad * 8,
                 &Kbuf[nxt][c * 512]);
        gl_lds16(Vbh + (size_t)(nt * 16 + l15) * Tc + (kt + 1) * 64 + ks * 32 + quad * 8,
                 &Vbuf[nxt][c * 512]);
      }
    }

    const bool diag = (kt == ktmax);

    // ---- S^T = K Q^T ----
    v4f st[4];
    #pragma unroll
    for (int nt = 0; nt < 4; ++nt) {
      v8bf k0 = *reinterpret_cast<const v8bf*>(&Kbuf[cur][(nt * 2 + 0) * 512 + lane * 8]);
      v8bf k1 = *reinterpret_cast<const v8bf*>(&Kbuf[cur][(nt * 2 + 1) * 512 + lane * 8]);
      st[nt] = (v4f){0.f, 0.f, 0.f, 0.f};
      st[nt] = __builtin_amdgcn_mfma_f32_16x16x32_bf16(k0, q0, st[nt], 0, 0, 0);
      st[nt] = __builtin_amdgcn_mfma_f32_16x16x32_bf16(k1, q1, st[nt], 0, 0, 0);
    }

    // ---- exp2 + causal mask -> P rows in per-wave LDS scratch ----
    #pragma unroll
    for (int nt = 0; nt < 4; ++nt) {
      uint2 pw;
      if (diag && nt > w) { pw.x = 0u; pw.y = 0u; }
      else {
        float p[4];
        #pragma unroll
        for (int i = 0; i < 4; ++i) {
          float e = __builtin_amdgcn_exp2f(st[nt][i] * SCALE_LOG2E);
          p[i] = (diag && nt == w && quad * 4 + i > l15) ? 0.f : e;
          ps += p[i];
        }
        pw.x = pack2bf(p[0], p[1]);
        pw.y = pack2bf(p[2], p[3]);
      }
      *reinterpret_cast<uint2*>(&Ps[(prow + nt * 16 + quad * 4) ^ swz]) = pw;
    }

    // ---- O^T += V^T P^T ; P B-fragment read directly from scratch ----
    const int kslim = (diag && w < 2) ? 1 : 2;
    #pragma unroll
    for (int ks = 0; ks < 2; ++ks) {
      if (ks >= kslim) continue;          // wave-uniform
      v8bf pb = *reinterpret_cast<const v8bf*>(&Ps[(prow + ks * 32 + quad * 8) ^ swz]);
      #pragma unroll
      for (int dt = 0; dt < 4; ++dt) {
        v8bf vf = *reinterpret_cast<const v8bf*>(&Vbuf[cur][(dt * 2 + ks) * 512 + lane * 8]);
        O[dt] = __builtin_amdgcn_mfma_f32_16x16x32_bf16(vf, pb, O[dt], 0, 0, 0);
      }
    }
  }

  // row sums for q=l15: reduce across the 4 quad groups
  ps += __shfl_xor(ps, 16);
  ps += __shfl_xor(ps, 32);
  const float inv = 1.f / ps;

  // O^T layout: lane holds q=l15, d = dt*16 + quad*4 + i -> packed b64 stores
  const int bb = bh >> 4, h = bh & 15;
  ushort_t* yp = yb + ((size_t)bb * Tc + s + l15) * Cc + h * Dc + quad * 4;
  #pragma unroll
  for (int dt = 0; dt < 4; ++dt) {
    uint2 pa;
    pa.x = pack2bf(O[dt][0] * inv, O[dt][1] * inv);
    pa.y = pack2bf(O[dt][2] * inv, O[dt][3] * inv);
    *reinterpret_cast<uint2*>(yp + dt * 16) = pa;
  }
}

// MFMA flash attention v12 (verified round 9): balanced sequential pairing
// (1024 blocks = 4/CU, uniform 33 iters) + LDS P-transform body. 40 KB LDS.
__global__ __launch_bounds__(256, 4) void flash_mfma12(const ushort_t* __restrict__ Qb,
                                                       const ushort_t* __restrict__ Kb,
                                                       const ushort_t* __restrict__ Vt,
                                                       ushort_t* __restrict__ yb) {
  const int x = blockIdx.x;                    // 0..15
  const int bh = blockIdx.y;
  const int jqA = 31 - x;                      // long item: 31..16 (longest first)
  const int jqB = x;                           // short item: 0..15
  const int t = threadIdx.x;
  const int w = t >> 6;
  const int lane = t & 63;
  const int quad = lane >> 4;
  const int l15 = lane & 15;

  __shared__ __align__(16) ushort_t Kbuf[2][8 * 512];   // 8 chunks x 1KiB, x2
  __shared__ __align__(16) ushort_t Vbuf[2][8 * 512];
  __shared__ __align__(16) ushort_t Pbuf[4][1024];      // per-wave 2KB P scratch

  flash_body(jqA, bh, w, lane, quad, l15, Qb, Kb, Vt, yb, Kbuf, Vbuf, &Pbuf[w][0]);
  __syncthreads();   // item A fully done with LDS before item B's prologue writes
  flash_body(jqB, bh, w, lane, quad, l15, Qb, Kb, Vt, yb, Kbuf, Vbuf, &Pbuf[w][0]);
}

extern "C" void kernel_launch(void* const* d_in, const int* in_sizes, int n_in,
                              void* d_out, int out_size, void* d_ws, size_t ws_size,
                              hipStream_t stream) {
  const float* x      = (const float*)d_in[0];   // [B,T,C]
  const float* w_attn = (const float*)d_in[1];   // [C,3C]
  const float* b_attn = (const float*)d_in[2];   // [3C]
  const float* w_proj = (const float*)d_in[3];   // [C,C]
  const float* b_proj = (const float*)d_in[4];   // [C]
  float* out = (float*)d_out;                    // [B,T,C] fp32

  const int M = Bc * Tc;        // 8192
  const int K = Cc;             // 1024
  const int N_qkv = 3 * Cc;     // 3072

  ushort_t* xb     = (ushort_t*)d_ws;                     // M*K        (16 MB)
  ushort_t* wattnT = xb + (size_t)M * K;                  // 3C*C       (6 MB)
  ushort_t* wprojT = wattnT + (size_t)N_qkv * K;          // C*C        (2 MB)
  ushort_t* Qb     = wprojT + (size_t)Cc * Cc;            // [bh,t,d]   (16 MB)
  ushort_t* Kb     = Qb + (size_t)M * Cc;                 // [bh,t,d]   (16 MB)
  ushort_t* Vt     = Kb + (size_t)M * Cc;                 // [bh,d,t]   (16 MB)
  ushort_t* yb     = Vt + (size_t)M * Cc;                 // [m,C]      (16 MB)

  int nx = M * K;
  cvt_bf16<<<(nx + 255) / 256, 256, 0, stream>>>(x, xb, nx);
  transpose_bf16t<<<dim3(N_qkv / 64, K / 64), 256, 0, stream>>>(w_attn, wattnT, K, N_qkv);
  transpose_bf16t<<<dim3(Cc / 64, K / 64), 256, 0, stream>>>(w_proj, wprojT, K, Cc);

  // qkv = x @ w_attn + b_attn  -> Qb/Kb ([bh,t,d]) and Vt ([bh,d,t]) bf16
  gemm128<1><<<dim3(N_qkv / 128, M / 128), 256, 0, stream>>>(
      xb, wattnT, b_attn, nullptr, Qb, Kb, Vt, M, N_qkv, K);

  // y = softmax(QK^T/sqrt(D)) V  (balanced pairing + LDS P-transform flash)
  flash_mfma12<<<dim3(Tc / 128, Bc * Hc), 256, 0, stream>>>(Qb, Kb, Vt, yb);

  // out = y @ w_proj + b_proj   (fp32 out)
  gemm128<0><<<dim3(Cc / 128, M / 128), 256, 0, stream>>>(
      yb, wprojT, b_proj, out, nullptr, nullptr, nullptr, M, Cc, K);
}

// Round 11
// 293.708 us; speedup vs baseline: 1.1727x; 1.1727x over previous
//
#include <hip/hip_runtime.h>
#include <cstdint>
#include <cstddef>

#define Bc 4
#define Tc 2048
#define Cc 1024
#define Hc 16
#define Dc 64

typedef unsigned short ushort_t;
typedef __bf16 v8bf __attribute__((ext_vector_type(8)));
typedef float v4f __attribute__((ext_vector_type(4)));

__device__ inline ushort_t f2bf(float f) {
  union { float f; unsigned int u; } v; v.f = f;
  unsigned int r = v.u + 0x7fffu + ((v.u >> 16) & 1u);  // RNE
  return (ushort_t)(r >> 16);
}

__device__ inline unsigned int pack2bf(float lo, float hi) {
  return (unsigned int)f2bf(lo) | ((unsigned int)f2bf(hi) << 16);
}

// async global->LDS, 16B per lane. LDS dest: wave-uniform base; HW adds lane*16.
__device__ inline void gl_lds16(const void* g, void* l) {
  __builtin_amdgcn_global_load_lds((__attribute__((address_space(1))) void*)g,
                                   (__attribute__((address_space(3))) void*)l,
                                   16, 0, 0);
}

// float -> bf16 elementwise
__global__ void cvt_bf16(const float* __restrict__ in, ushort_t* __restrict__ out, int n) {
  int i = blockIdx.x * blockDim.x + threadIdx.x;
  if (i < n) out[i] = f2bf(in[i]);
}

// w [K,N] f32 -> wt [N,K] bf16, tiled via LDS (coalesced both sides)
__global__ __launch_bounds__(256) void transpose_bf16t(const float* __restrict__ w,
                                                       ushort_t* __restrict__ wt,
                                                       int K, int N) {
  __shared__ float tile[64][65];
  const int t = threadIdx.x;
  const int n0 = blockIdx.x * 64;
  const int k0 = blockIdx.y * 64;
  #pragma unroll
  for (int i = 0; i < 16; ++i) {
    int r = (t >> 6) + i * 4, c = t & 63;
    tile[r][c] = w[(size_t)(k0 + r) * N + n0 + c];
  }
  __syncthreads();
  #pragma unroll
  for (int i = 0; i < 16; ++i) {
    int r = (t >> 6) + i * 4, c = t & 63;
    wt[(size_t)(n0 + r) * K + k0 + c] = f2bf(tile[c][r]);
  }
}

// m97-style 128x128 GEMM, BK=32, 4 waves, global_load_lds staging, 2-phase
// double-buffered K-loop (ROUND-9 VERIFIED VERSION, reverted from the failed
// B-register experiment). Used for the proj GEMM (MODE 0) only.
template <int MODE>
__global__ __launch_bounds__(256) void gemm128(const ushort_t* __restrict__ A,
                                               const ushort_t* __restrict__ BT,
                                               const float* __restrict__ bias,
                                               float* __restrict__ Cout,
                                               ushort_t* __restrict__ Qb,
                                               ushort_t* __restrict__ Kb,
                                               ushort_t* __restrict__ Vt,
                                               int M, int N, int K) {
  __shared__ __align__(16) unsigned char smem[32768];

  const int t = threadIdx.x;
  const int wave = t >> 6;
  const int lane = t & 63;
  const int quad = lane >> 4;
  const int l15 = lane & 15;
  const int m0 = blockIdx.y * 128;
  const int n0 = blockIdx.x * 128;
  const int wm = wave >> 1, wn = wave & 1;

  v4f acc[4][4];
  #pragma unroll
  for (int mi = 0; mi < 4; ++mi)
    #pragma unroll
    for (int ni = 0; ni < 4; ++ni) acc[mi][ni] = (v4f){0.f, 0.f, 0.f, 0.f};

  const int NK = K >> 5;

  const int srow0 = t >> 2, ssc = (t & 3) * 8;
  const int srow1 = (t + 256) >> 2;
  const int sbase0 = (t & ~63) * 8;
  const int sbase1 = ((t & ~63) + 256) * 8;

  {
    ushort_t* As = (ushort_t*)smem;
    ushort_t* Bs = (ushort_t*)(smem + 8192);
    gl_lds16(A + (size_t)(m0 + srow0) * K + ssc, &As[sbase0]);
    gl_lds16(BT + (size_t)(n0 + srow0) * K + ssc, &Bs[sbase0]);
    gl_lds16(A + (size_t)(m0 + srow1) * K + ssc, &As[sbase1]);
    gl_lds16(BT + (size_t)(n0 + srow1) * K + ssc, &Bs[sbase1]);
  }

  for (int kk = 0; kk < NK; ++kk) {
    const int bi = kk & 1;
    __syncthreads();
    if (kk + 1 < NK) {
      const int kc = (kk + 1) * 32;
      ushort_t* As = (ushort_t*)(smem + (bi ^ 1) * 16384);
      ushort_t* Bs = (ushort_t*)(smem + (bi ^ 1) * 16384 + 8192);
      gl_lds16(A + (size_t)(m0 + srow0) * K + kc + ssc, &As[sbase0]);
      gl_lds16(BT + (size_t)(n0 + srow0) * K + kc + ssc, &Bs[sbase0]);
      gl_lds16(A + (size_t)(m0 + srow1) * K + kc + ssc, &As[sbase1]);
      gl_lds16(BT + (size_t)(n0 + srow1) * K + kc + ssc, &Bs[sbase1]);
    }

    const ushort_t* As = (const ushort_t*)(smem + bi * 16384);
    const ushort_t* Bs = (const ushort_t*)(smem + bi * 16384 + 8192);
    v8bf a[4], b[4];
    #pragma unroll
    for (int mi = 0; mi < 4; ++mi)
      a[mi] = *reinterpret_cast<const v8bf*>(&As[(wm * 64 + mi * 16 + l15) * 32 + quad * 8]);
    #pragma unroll
    for (int ni = 0; ni < 4; ++ni)
      b[ni] = *reinterpret_cast<const v8bf*>(&Bs[(wn * 64 + ni * 16 + l15) * 32 + quad * 8]);
    #pragma unroll
    for (int mi = 0; mi < 4; ++mi)
      #pragma unroll
      for (int ni = 0; ni < 4; ++ni)
        acc[mi][ni] = __builtin_amdgcn_mfma_f32_16x16x32_bf16(a[mi], b[ni], acc[mi][ni], 0, 0, 0);
  }
  __syncthreads();

  if (MODE == 0) {
    #pragma unroll
    for (int ni = 0; ni < 4; ++ni) {
      const int n_g = n0 + wn * 64 + ni * 16 + l15;
      const float bv = bias[n_g];
      #pragma unroll
      for (int mi = 0; mi < 4; ++mi)
        #pragma unroll
        for (int i = 0; i < 4; ++i) {
          int m_g = m0 + wm * 64 + mi * 16 + quad * 4 + i;
          Cout[(size_t)m_g * N + n_g] = acc[mi][ni][i] + bv;
        }
    }
  }
}

// ============================================================================
// gemm256_qkv: 256x256 8-phase GEMM for the qkv projection (guide §5.5 T3+T4).
// BK=64 split into two 32-wide k-chunks; LDS = [A|B][2 dbuf][2 kh][256][32]
// bf16 = 128 KB (dynamic). 512 threads = 8 waves (2M x 4N), per-wave output
// 128x64 (acc[8][4]). Per K-tile: 4 phases, each {ds_read 4-8 b128, stage one
// 16KB chunk of tile j+1, s_barrier, lgkmcnt(0), setprio(1), 16 MFMA,
// setprio(0), counted vmcnt drain at phases 1/3, s_barrier}. vmcnt(4) keeps 4
// staging loads in flight across barriers (T4: never drain to 0 mid-loop).
// Chunk rows are 64 B apart -> fragment ds_reads hit the b128 bank floor
// (no swizzle needed). sched_barrier(0) after each s_barrier pins LDS reads
// below the visibility barrier (per-wave vmcnt + barrier = all-wave landed).
// Epilogue: 4 passes of 64 m-rows through LDS restaging -> coalesced
// [bh,t,d] rows for Q/K and transposed [bh,d,t] rows for V.
// ============================================================================
__global__ __launch_bounds__(512, 1) void gemm256_qkv(const ushort_t* __restrict__ A,
                                                      const ushort_t* __restrict__ BT,
                                                      const float* __restrict__ bias,
                                                      ushort_t* __restrict__ Qb,
                                                      ushort_t* __restrict__ Kb,
                                                      ushort_t* __restrict__ Vt,
                                                      int K) {
  extern __shared__ __align__(16) ushort_t lds[];
  ushort_t* Ab = lds;            // [2][2][256][32] ushort = 32768
  ushort_t* Bb = lds + 32768;

  const int t = threadIdx.x;
  const int wid = t >> 6;
  const int lane = t & 63;
  const int quad = lane >> 4;
  const int l15 = lane & 15;
  const int wr = wid >> 2;       // 0..1  (M half)
  const int wc = wid & 3;        // 0..3  (N quarter)
  const int m0 = blockIdx.y * 256;
  const int n0 = blockIdx.x * 256;
  const int NKT = K >> 6;        // 16

  v4f acc[8][4];
  #pragma unroll
  for (int mi = 0; mi < 8; ++mi)
    #pragma unroll
    for (int ni = 0; ni < 4; ++ni) acc[mi][ni] = (v4f){0.f, 0.f, 0.f, 0.f};

  // staging geometry: chunk = [256 rows][32 k] bf16 = 16 KB = 2 sweeps of
  // 8 waves x 1 KB. sweep s: rows s*128 + wid*16 + lane/4, k-col (lane&3)*8.
  const int sr = wid * 16 + (lane >> 2);
  const int sc = (lane & 3) * 8;
  const int ldst = wid * 512;          // ushort offset within chunk (+ s*4096)

  // prologue: tile 0 chunks A0,B0,A1,B1 -> buffer 0
  #pragma unroll
  for (int ch = 0; ch < 4; ++ch) {
    const int op = ch & 1, kh = ch >> 1;
    #pragma unroll
    for (int s = 0; s < 2; ++s) {
      const ushort_t* g = (op ? BT : A) +
          (size_t)((op ? n0 : m0) + s * 128 + sr) * K + kh * 32 + sc;
      ushort_t* d = (op ? Bb : Ab) + kh * 8192 + ldst + s * 4096;
      gl_lds16(g, d);
    }
  }
  asm volatile("s_waitcnt vmcnt(4)" ::: "memory");   // A0,B0 landed (own share)
  __builtin_amdgcn_s_barrier();                       // all waves' shares landed
  __builtin_amdgcn_sched_barrier(0);

  for (int j = 0; j < NKT; ++j) {
    const int db = (j & 1) * 16384;    // current buffer (ushort offset)
    const int dbn = 16384 - db;        // next buffer
    const bool pre = (j + 1 < NKT);
    v8bf a_[4], b_[4];

#define GQ_STAGE(CH)                                                          \
    if (pre) {                                                                \
      const int op_ = (CH) & 1, kh_ = (CH) >> 1;                              \
      _Pragma("unroll")                                                       \
      for (int s = 0; s < 2; ++s) {                                           \
        const ushort_t* g_ = (op_ ? BT : A) +                                 \
            (size_t)((op_ ? n0 : m0) + s * 128 + sr) * K + (j + 1) * 64 +     \
            kh_ * 32 + sc;                                                    \
        ushort_t* d_ = (op_ ? Bb : Ab) + dbn + kh_ * 8192 + ldst + s * 4096;  \
        gl_lds16(g_, d_);                                                     \
      }                                                                       \
    }

#define GQ_READ_A(MIH, KS)                                                    \
    _Pragma("unroll")                                                         \
    for (int q = 0; q < 4; ++q)                                               \
      a_[q] = *reinterpret_cast<const v8bf*>(                                 \
          &Ab[db + (KS) * 8192 + (wr * 128 + ((MIH) * 4 + q) * 16 + l15) * 32 \
              + quad * 8]);

#define GQ_READ_B(KS)                                                         \
    _Pragma("unroll")                                                         \
    for (int ni = 0; ni < 4; ++ni)                                            \
      b_[ni] = *reinterpret_cast<const v8bf*>(                                \
          &Bb[db + (KS) * 8192 + (wc * 64 + ni * 16 + l15) * 32 + quad * 8]);

#define GQ_MFMA(MIH)                                                          \
    __builtin_amdgcn_s_barrier();                                             \
    __builtin_amdgcn_sched_barrier(0);                                        \
    asm volatile("s_waitcnt lgkmcnt(0)" ::: "memory");                        \
    __builtin_amdgcn_sched_barrier(0);                                        \
    __builtin_amdgcn_s_setprio(1);                                            \
    _Pragma("unroll")                                                         \
    for (int q = 0; q < 4; ++q) {                                             \
      _Pragma("unroll")                                                       \
      for (int ni = 0; ni < 4; ++ni)                                          \
        acc[(MIH) * 4 + q][ni] = __builtin_amdgcn_mfma_f32_16x16x32_bf16(     \
            a_[q], b_[ni], acc[(MIH) * 4 + q][ni], 0, 0, 0);                  \
    }                                                                         \
    __builtin_amdgcn_s_setprio(0);

    // ---- phase 0: ks=0, mi 0-3; stage A-kh0(j+1) ----
    GQ_READ_A(0, 0)
    GQ_READ_B(0)
    GQ_STAGE(0)
    GQ_MFMA(0)
    __builtin_amdgcn_s_barrier();
    __builtin_amdgcn_sched_barrier(0);

    // ---- phase 1: ks=0, mi 4-7; stage B-kh0(j+1); drain for kh1 ----
    GQ_READ_A(1, 0)
    GQ_STAGE(1)
    GQ_MFMA(1)
    if (pre) { asm volatile("s_waitcnt vmcnt(4)" ::: "memory"); }
    else     { asm volatile("s_waitcnt vmcnt(0)" ::: "memory"); }
    __builtin_amdgcn_s_barrier();
    __builtin_amdgcn_sched_barrier(0);

    // ---- phase 2: ks=1, mi 0-3; stage A-kh1(j+1) ----
    GQ_READ_A(0, 1)
    GQ_READ_B(1)
    GQ_STAGE(2)
    GQ_MFMA(0)
    __builtin_amdgcn_s_barrier();
    __builtin_amdgcn_sched_barrier(0);

    // ---- phase 3: ks=1, mi 4-7; stage B-kh1(j+1); drain for next tile ----
    GQ_READ_A(1, 1)
    GQ_STAGE(3)
    GQ_MFMA(1)
    if (pre) { asm volatile("s_waitcnt vmcnt(4)" ::: "memory"); }
    __builtin_amdgcn_s_barrier();
    __builtin_amdgcn_sched_barrier(0);

#undef GQ_STAGE
#undef GQ_READ_A
#undef GQ_READ_B
#undef GQ_MFMA
  }

  // ------------------- epilogue (LDS now free for restaging) -----------------
  const int part = n0 >> 10;            // 0:Q 1:K 2:V (256 | 1024, no straddle)
  ushort_t* Cs = lds;
  const int bb = m0 >> 11, tt0 = m0 & 2047;

  if (part < 2) {
    ushort_t* dst = (part == 0) ? Qb : Kb;
    const int hbase = (n0 & 1023) >> 6;
    #pragma unroll
    for (int p = 0; p < 4; ++p) {
      if (wr == (p >> 1)) {
        #pragma unroll
        for (int ni = 0; ni < 4; ++ni) {
          const int c = wc * 64 + ni * 16 + l15;
          const float bv = bias[n0 + c];
          #pragma unroll
          for (int q = 0; q < 4; ++q) {
            const int mi = (p & 1) * 4 + q;
            #pragma unroll
            for (int i = 0; i < 4; ++i)
              Cs[(q * 16 + quad * 4 + i) * 264 + c] = f2bf(acc[mi][ni][i] + bv);
          }
        }
      }
      __syncthreads();
      {
        const int r = t >> 3, cu = (t & 7) * 32;
        const int m_g = m0 + p * 64 + r;
        const int tt = m_g & 2047;
        const int h = hbase + (cu >> 6);
        ushort_t* gp = dst + (((size_t)(m_g >> 11) * Hc + h) * Tc + tt) * Dc + (cu & 63);
        const ushort_t* sp = &Cs[r * 264 + cu];
        #pragma unroll
        for (int jj = 0; jj < 4; ++jj)
          *reinterpret_cast<uint4*>(gp + jj * 8) = *reinterpret_cast<const uint4*>(sp + jj * 8);
      }
      __syncthreads();
    }
  } else {
    const int h0 = (n0 >> 6) - 32;
    #pragma unroll
    for (int p = 0; p < 4; ++p) {
      if (wr == (p >> 1)) {
        #pragma unroll
        for (int ni = 0; ni < 4; ++ni) {
          const int n_l = wc * 64 + ni * 16 + l15;
          const float bv = bias[n0 + n_l];
          #pragma unroll
          for (int q = 0; q < 4; ++q) {
            const int mi = (p & 1) * 4 + q;
            #pragma unroll
            for (int i = 0; i < 4; ++i)
              Cs[n_l * 72 + q * 16 + quad * 4 + i] = f2bf(acc[mi][ni][i] + bv);
          }
        }
      }
      __syncthreads();
      {
        const int n_l = t >> 1, c0 = (t & 1) * 32;
        const int d = n_l & 63, hh = n_l >> 6;
        ushort_t* gp = Vt + (((size_t)bb * Hc + h0 + hh) * Dc + d) * Tc + tt0 + p * 64 + c0;
        const ushort_t* sp = &Cs[n_l * 72 + c0];
        #pragma unroll
        for (int jj = 0; jj < 4; ++jj)
          *reinterpret_cast<uint4*>(gp + jj * 8) = *reinterpret_cast<const uint4*>(sp + jj * 8);
      }
      __syncthreads();
    }
  }
}

// One q-tile slab of flash attention (v10 structure) with the LDS P-transform
// (verified round 9): P written to per-wave scratch (XOR-swizzled ds_write_b64)
// and read back as PV B-fragments (2x ds_read_b128).
__device__ __forceinline__ void flash_body(int jq, int bh, int w, int lane, int quad, int l15,
                                           const ushort_t* __restrict__ Qb,
                                           const ushort_t* __restrict__ Kb,
                                           const ushort_t* __restrict__ Vt,
                                           ushort_t* __restrict__ yb,
                                           ushort_t (*Kbuf)[8 * 512],
                                           ushort_t (*Vbuf)[8 * 512],
                                           ushort_t* __restrict__ Ps) {
  const int ktmax = jq;
  const int s = jq * 64 + w * 16;

  const ushort_t* Kbh = Kb + (size_t)bh * (Tc * Dc);
  const ushort_t* Vbh = Vt + (size_t)bh * (Dc * Tc);

  const ushort_t* qp = Qb + ((size_t)bh * Tc + s + l15) * Dc;
  v8bf q0 = *reinterpret_cast<const v8bf*>(qp + quad * 8);
  v8bf q1 = *reinterpret_cast<const v8bf*>(qp + 32 + quad * 8);

  v4f O[4];
  #pragma unroll
  for (int i = 0; i < 4; ++i) O[i] = (v4f){0.f, 0.f, 0.f, 0.f};
  float ps = 0.f;
  const float SCALE_LOG2E = 0.125f * 1.44269504f;

  const int swz = (l15 & 7) << 3;
  const int prow = l15 * 64;

  #pragma unroll
  for (int it = 0; it < 2; ++it) {
    int c = w + it * 4, nt = c >> 1, ks = c & 1;
    gl_lds16(Kbh + (size_t)(nt * 16 + l15) * Dc + ks * 32 + quad * 8, &Kbuf[0][c * 512]);
    gl_lds16(Vbh + (size_t)(nt * 16 + l15) * Tc + ks * 32 + quad * 8, &Vbuf[0][c * 512]);
  }

  for (int kt = 0; kt <= ktmax; ++kt) {
    __syncthreads();
    const int cur = kt & 1;
    if (kt < ktmax) {
      const int nxt = cur ^ 1;
      #pragma unroll
      for (int it = 0; it < 2; ++it) {
        int c = w + it * 4, nt = c >> 1, ks = c & 1;
        gl_lds16(Kbh + (size_t)((kt + 1) * 64 + nt * 16 + l15) * Dc + ks * 32 + quad * 8,
                 &Kbuf[nxt][c * 512]);
        gl_lds16(Vbh + (size_t)(nt * 16 + l15) * Tc + (kt + 1) * 64 + ks * 32 + quad * 8,
                 &Vbuf[nxt][c * 512]);
      }
    }

    const bool diag = (kt == ktmax);

    v4f st[4];
    #pragma unroll
    for (int nt = 0; nt < 4; ++nt) {
      v8bf k0 = *reinterpret_cast<const v8bf*>(&Kbuf[cur][(nt * 2 + 0) * 512 + lane * 8]);
      v8bf k1 = *reinterpret_cast<const v8bf*>(&Kbuf[cur][(nt * 2 + 1) * 512 + lane * 8]);
      st[nt] = (v4f){0.f, 0.f, 0.f, 0.f};
      st[nt] = __builtin_amdgcn_mfma_f32_16x16x32_bf16(k0, q0, st[nt], 0, 0, 0);
      st[nt] = __builtin_amdgcn_mfma_f32_16x16x32_bf16(k1, q1, st[nt], 0, 0, 0);
    }

    #pragma unroll
    for (int nt = 0; nt < 4; ++nt) {
      uint2 pw;
      if (diag && nt > w) { pw.x = 0u; pw.y = 0u; }
      else {
        float p[4];
        #pragma unroll
        for (int i = 0; i < 4; ++i) {
          float e = __builtin_amdgcn_exp2f(st[nt][i] * SCALE_LOG2E);
          p[i] = (diag && nt == w && quad * 4 + i > l15) ? 0.f : e;
          ps += p[i];
        }
        pw.x = pack2bf(p[0], p[1]);
        pw.y = pack2bf(p[2], p[3]);
      }
      *reinterpret_cast<uint2*>(&Ps[(prow + nt * 16 + quad * 4) ^ swz]) = pw;
    }

    const int kslim = (diag && w < 2) ? 1 : 2;
    #pragma unroll
    for (int ks = 0; ks < 2; ++ks) {
      if (ks >= kslim) continue;
      v8bf pb = *reinterpret_cast<const v8bf*>(&Ps[(prow + ks * 32 + quad * 8) ^ swz]);
      #pragma unroll
      for (int dt = 0; dt < 4; ++dt) {
        v8bf vf = *reinterpret_cast<const v8bf*>(&Vbuf[cur][(dt * 2 + ks) * 512 + lane * 8]);
        O[dt] = __builtin_amdgcn_mfma_f32_16x16x32_bf16(vf, pb, O[dt], 0, 0, 0);
      }
    }
  }

  ps += __shfl_xor(ps, 16);
  ps += __shfl_xor(ps, 32);
  const float inv = 1.f / ps;

  const int bb = bh >> 4, h = bh & 15;
  ushort_t* yp = yb + ((size_t)bb * Tc + s + l15) * Cc + h * Dc + quad * 4;
  #pragma unroll
  for (int dt = 0; dt < 4; ++dt) {
    uint2 pa;
    pa.x = pack2bf(O[dt][0] * inv, O[dt][1] * inv);
    pa.y = pack2bf(O[dt][2] * inv, O[dt][3] * inv);
    *reinterpret_cast<uint2*>(yp + dt * 16) = pa;
  }
}

// MFMA flash attention v12 (verified round 9): balanced sequential pairing
// (1024 blocks = 4/CU, uniform 33 iters) + LDS P-transform body. 40 KB LDS.
__global__ __launch_bounds__(256, 4) void flash_mfma12(const ushort_t* __restrict__ Qb,
                                                       const ushort_t* __restrict__ Kb,
                                                       const ushort_t* __restrict__ Vt,
                                                       ushort_t* __restrict__ yb) {
  const int x = blockIdx.x;
  const int bh = blockIdx.y;
  const int jqA = 31 - x;
  const int jqB = x;
  const int t = threadIdx.x;
  const int w = t >> 6;
  const int lane = t & 63;
  const int quad = lane >> 4;
  const int l15 = lane & 15;

  __shared__ __align__(16) ushort_t Kbuf[2][8 * 512];
  __shared__ __align__(16) ushort_t Vbuf[2][8 * 512];
  __shared__ __align__(16) ushort_t Pbuf[4][1024];

  flash_body(jqA, bh, w, lane, quad, l15, Qb, Kb, Vt, yb, Kbuf, Vbuf, &Pbuf[w][0]);
  __syncthreads();
  flash_body(jqB, bh, w, lane, quad, l15, Qb, Kb, Vt, yb, Kbuf, Vbuf, &Pbuf[w][0]);
}

extern "C" void kernel_launch(void* const* d_in, const int* in_sizes, int n_in,
                              void* d_out, int out_size, void* d_ws, size_t ws_size,
                              hipStream_t stream) {
  const float* x      = (const float*)d_in[0];   // [B,T,C]
  const float* w_attn = (const float*)d_in[1];   // [C,3C]
  const float* b_attn = (const float*)d_in[2];   // [3C]
  const float* w_proj = (const float*)d_in[3];   // [C,C]
  const float* b_proj = (const float*)d_in[4];   // [C]
  float* out = (float*)d_out;                    // [B,T,C] fp32

  const int M = Bc * Tc;        // 8192
  const int K = Cc;             // 1024
  const int N_qkv = 3 * Cc;     // 3072

  ushort_t* xb     = (ushort_t*)d_ws;                     // M*K        (16 MB)
  ushort_t* wattnT = xb + (size_t)M * K;                  // 3C*C       (6 MB)
  ushort_t* wprojT = wattnT + (size_t)N_qkv * K;          // C*C        (2 MB)
  ushort_t* Qb     = wprojT + (size_t)Cc * Cc;            // [bh,t,d]   (16 MB)
  ushort_t* Kb     = Qb + (size_t)M * Cc;                 // [bh,t,d]   (16 MB)
  ushort_t* Vt     = Kb + (size_t)M * Cc;                 // [bh,d,t]   (16 MB)
  ushort_t* yb     = Vt + (size_t)M * Cc;                 // [m,C]      (16 MB)

  int nx = M * K;
  cvt_bf16<<<(nx + 255) / 256, 256, 0, stream>>>(x, xb, nx);
  transpose_bf16t<<<dim3(N_qkv / 64, K / 64), 256, 0, stream>>>(w_attn, wattnT, K, N_qkv);
  transpose_bf16t<<<dim3(Cc / 64, K / 64), 256, 0, stream>>>(w_proj, wprojT, K, Cc);

  // qkv = x @ w_attn + b_attn (256x256 8-phase, 128 KB dynamic LDS)
  hipFuncSetAttribute((const void*)gemm256_qkv,
                      hipFuncAttributeMaxDynamicSharedMemorySize, 131072);
  gemm256_qkv<<<dim3(N_qkv / 256, M / 256), 512, 131072, stream>>>(
      xb, wattnT, b_attn, Qb, Kb, Vt, K);

  // y = softmax(QK^T/sqrt(D)) V  (balanced pairing + LDS P-transform flash)
  flash_mfma12<<<dim3(Tc / 128, Bc * Hc), 256, 0, stream>>>(Qb, Kb, Vt, yb);

  // out = y @ w_proj + b_proj   (fp32 out, 2-phase 128x128)
  gemm128<0><<<dim3(Cc / 128, M / 128), 256, 0, stream>>>(
      yb, wprojT, b_proj, out, nullptr, nullptr, nullptr, M, Cc, K);
}